// Round 3
// baseline (643.471 us; speedup 1.0000x reference)
//
#include <hip/hip_runtime.h>

// Problem constants
#define Bb 16
#define Nn 16384
#define Ll 192
#define Ee 128
#define Dd 128

// Output element offsets (fp32 elements) within d_out:
// obs:     0          (16*16384*128 = 33554432)
// temp_he: 33554432   (16*192*128   =   393216)
// out:     33947648   (16*128*128   =   262144)
// ti:      34209792   (16*192*16384 = 50331648)
// vi:      84541440   (16*128*16384 = 33554432)   [ti+vi contiguous]

// ---------------------------------------------------------------------------
// Kernel 1: obs features + ti/vi scatter + per-(b,e) mask histogram.
// One 256-thread block = 4 rows (b,n); 64 lanes/row, 2 outputs/lane.
// ---------------------------------------------------------------------------
__global__ __launch_bounds__(256) void k_obs(
    const float* __restrict__ x, const float* __restrict__ mask,
    const float* __restrict__ ymask, const int* __restrict__ vidx,
    const int* __restrict__ tidx, const float* __restrict__ W_obs,
    const float* __restrict__ b_obs, float* __restrict__ obs,
    float* __restrict__ ti, float* __restrict__ vi, float* __restrict__ cnt)
{
    const int row  = (blockIdx.x << 2) + (threadIdx.x >> 6);
    const int lane = threadIdx.x & 63;
    const int b = row >> 14;        // N = 16384 = 2^14
    const int n = row & (Nn - 1);

    const float m  = mask[row];
    const float xv = x[row];
    const float f1 = 1.0f - m + ymask[row];

    const int d = lane << 1;
    const float w00 = W_obs[d],      w01 = W_obs[d + 1];
    const float w10 = W_obs[Dd + d], w11 = W_obs[Dd + d + 1];
    const float bb0 = b_obs[d],      bb1 = b_obs[d + 1];

    float2 ov;
    ov.x = fmaxf(fmaf(xv, w00, fmaf(f1, w10, bb0)), 0.0f) * m;
    ov.y = fmaxf(fmaf(xv, w01, fmaf(f1, w11, bb1)), 0.0f) * m;
    *reinterpret_cast<float2*>(obs + ((size_t)row << 7) + d) = ov;

    if (lane == 0 && m != 0.0f) {
        const int t = tidx[row];
        const int e = vidx[row];
        ti[(size_t)b * (Ll * (size_t)Nn) + (size_t)t * Nn + n] = m;  // m == 1.0
        vi[((size_t)(b * Ee + e) << 14) + n] = m;
        atomicAdd(&cnt[b * Ee + e], 1.0f);
    }
}

// ---------------------------------------------------------------------------
// Kernel 2: temp_he = sin(mark * W_time + b_time), elementwise over B*L*D
// ---------------------------------------------------------------------------
__global__ __launch_bounds__(256) void k_temp(
    const float* __restrict__ mark, const float* __restrict__ Wt,
    const float* __restrict__ bt, float* __restrict__ temp)
{
    const int idx = blockIdx.x * 256 + threadIdx.x;   // < 393216
    const int d = idx & 127;
    const int r = idx >> 7;
    temp[idx] = sinf(fmaf(mark[r], Wt[d], bt[d]));
}

// ---------------------------------------------------------------------------
// Kernel 3: q,k,v = relu(var_w) @ W_{q,k,v} + b  (batch-independent, fp32 ws)
// One block per hyperedge row e; thread d computes column d of all three.
// ---------------------------------------------------------------------------
__global__ __launch_bounds__(128) void k_qkv(
    const float* __restrict__ var_w,
    const float* __restrict__ Wq, const float* __restrict__ bq,
    const float* __restrict__ Wk, const float* __restrict__ bk,
    const float* __restrict__ Wv, const float* __restrict__ bv,
    float* __restrict__ q, float* __restrict__ k, float* __restrict__ v)
{
    __shared__ float h[Dd];
    const int e = blockIdx.x, d = threadIdx.x;
    h[d] = fmaxf(var_w[e * Dd + d], 0.0f);
    __syncthreads();
    float aq = bq[d], ak = bk[d], av = bv[d];
    #pragma unroll 4
    for (int j = 0; j < Dd; ++j) {
        const float hj = h[j];
        aq = fmaf(hj, Wq[j * Dd + d], aq);
        ak = fmaf(hj, Wk[j * Dd + d], ak);
        av = fmaf(hj, Wv[j * Dd + d], av);
    }
    q[e * Dd + d] = aq;
    k[e * Dd + d] = ak;
    v[e * Dd + d] = av;
}

// ---------------------------------------------------------------------------
// Kernel 4: att0 = q @ k^T / sqrt(D)  (batch-independent, fp32)
// ---------------------------------------------------------------------------
__global__ __launch_bounds__(128) void k_att0(
    const float* __restrict__ q, const float* __restrict__ k,
    float* __restrict__ att0)
{
    __shared__ float qr[Dd];
    const int e = blockIdx.x, f = threadIdx.x;
    qr[f] = q[e * Dd + f];
    __syncthreads();
    const float* kr = k + f * Dd;
    float acc = 0.0f;
    #pragma unroll 4
    for (int d = 0; d < Dd; ++d) acc = fmaf(qr[d], kr[d], acc);
    att0[e * Dd + f] = acc * 0.08838834764831845f;   // 1/sqrt(128)
}

// ---------------------------------------------------------------------------
// Kernel 5: per-(b,e): diagonal merge-adjust, softmax over f, out = attn @ v
// Grid = B*E blocks of 128 threads (2 waves).
// ---------------------------------------------------------------------------
__global__ __launch_bounds__(128) void k_soft(
    const float* __restrict__ att0, const float* __restrict__ v,
    const float* __restrict__ cnt, const float* __restrict__ thr_p,
    const float* __restrict__ mc_p, const int* __restrict__ nobs_p,
    float* __restrict__ outp)
{
    __shared__ float attn[Ee];
    __shared__ float red[4];
    const int b = blockIdx.x >> 7;
    const int e = blockIdx.x & 127;
    const int f = threadIdx.x;

    float a = att0[e * Ee + f];
    if (f == e) {
        const float c = cnt[b * Ee + e];
        const float thr = *thr_p;
        if (c != 0.0f && a > thr) {
            const float mc  = *mc_p;
            const float aux = c / sqrtf((float)(*nobs_p));
            a = (1.0f - mc) * a + mc * aux;
        }
    }
    // block max (2 waves): wave shuffle reduce, combine through LDS
    float mx = a;
    #pragma unroll
    for (int off = 32; off > 0; off >>= 1) mx = fmaxf(mx, __shfl_xor(mx, off));
    if ((threadIdx.x & 63) == 0) red[threadIdx.x >> 6] = mx;
    __syncthreads();
    mx = fmaxf(red[0], red[1]);

    const float ex = expf(a - mx);
    float s = ex;
    #pragma unroll
    for (int off = 32; off > 0; off >>= 1) s += __shfl_xor(s, off);
    if ((threadIdx.x & 63) == 0) red[2 + (threadIdx.x >> 6)] = s;
    __syncthreads();
    s = red[2] + red[3];

    attn[f] = ex / s;
    __syncthreads();

    const int d = f;
    float acc = 0.0f;
    #pragma unroll 4
    for (int j = 0; j < Ee; ++j) acc = fmaf(attn[j], v[j * Dd + d], acc);
    outp[((size_t)(b * Ee + e) << 7) + d] = acc;
}

// ---------------------------------------------------------------------------
extern "C" void kernel_launch(void* const* d_in, const int* in_sizes, int n_in,
                              void* d_out, int out_size, void* d_ws, size_t ws_size,
                              hipStream_t stream) {
    (void)in_sizes; (void)n_in; (void)out_size; (void)ws_size;

    const float* x      = (const float*)d_in[0];
    const float* mask   = (const float*)d_in[1];
    const float* ymask  = (const float*)d_in[2];
    const float* mark   = (const float*)d_in[3];
    const int*   vidx   = (const int*)d_in[4];
    const int*   tidx   = (const int*)d_in[5];
    const int*   nobs   = (const int*)d_in[6];
    const float* W_obs  = (const float*)d_in[7];
    const float* b_obs  = (const float*)d_in[8];
    const float* W_time = (const float*)d_in[9];
    const float* b_time = (const float*)d_in[10];
    const float* var_w  = (const float*)d_in[11];
    const float* W_q    = (const float*)d_in[12];
    const float* b_q    = (const float*)d_in[13];
    const float* W_k    = (const float*)d_in[14];
    const float* b_k    = (const float*)d_in[15];
    const float* W_v    = (const float*)d_in[16];
    const float* b_v    = (const float*)d_in[17];
    const float* thr    = (const float*)d_in[18];
    const float* mc     = (const float*)d_in[19];

    float* out_base = (float*)d_out;
    float* obs  = out_base;
    float* temp = out_base + 33554432;
    float* attO = out_base + 33947648;
    float* ti   = out_base + 34209792;
    float* vi   = out_base + 84541440;

    // ws layout (fp32): cnt[2048] | q[16384] | k[16384] | v[16384] | att0[16384]
    float* ws   = (float*)d_ws;
    float* cnt  = ws;
    float* q    = ws + 2048;
    float* k    = ws + 18432;
    float* v    = ws + 34816;
    float* att0 = ws + 51200;

    // zero ti+vi (contiguous, 83886080 fp32 = 335.5 MB) and the histogram
    hipMemsetAsync(ti, 0, (size_t)(50331648 + 33554432) * sizeof(float), stream);
    hipMemsetAsync(cnt, 0, 2048 * sizeof(float), stream);

    k_obs<<<(Bb * Nn) / 4, 256, 0, stream>>>(x, mask, ymask, vidx, tidx,
                                             W_obs, b_obs, obs, ti, vi, cnt);
    k_temp<<<(Bb * Ll * Dd) / 256, 256, 0, stream>>>(mark, W_time, b_time, temp);
    k_qkv<<<Ee, Dd, 0, stream>>>(var_w, W_q, b_q, W_k, b_k, W_v, b_v, q, k, v);
    k_att0<<<Ee, Dd, 0, stream>>>(q, k, att0);
    k_soft<<<Bb * Ee, Dd, 0, stream>>>(att0, v, cnt, thr, mc, nobs, attO);
}

// Round 4
// 590.950 us; speedup vs baseline: 1.0889x; 1.0889x over previous
//
#include <hip/hip_runtime.h>

// Problem constants
#define Bb 16
#define Nn 16384
#define Ll 192
#define Ee 128
#define Dd 128

// Output element offsets (fp32 elements) within d_out:
// obs:     0          (16*16384*128 = 33554432)
// temp_he: 33554432   (16*192*128   =   393216)
// out:     33947648   (16*128*128   =   262144)
// ti:      34209792   (16*192*16384 = 50331648)
// vi:      84541440   (16*128*16384 = 33554432)   [ti+vi contiguous]

// ---------------------------------------------------------------------------
// Kernel 1: dense ti/vi incidence write + per-(b,e) histogram via LDS.
// Thread owns float4 along n for one b. 256 blocks x 256 threads;
// 16 blocks per b (4096 threads x 4 n each = 16384 = N).
// All stores fully coalesced (1 KB per wave per row). No memset needed.
// ---------------------------------------------------------------------------
__global__ __launch_bounds__(256) void k_inc(
    const int* __restrict__ tidx, const int* __restrict__ vidx,
    const float* __restrict__ mask,
    float* __restrict__ ti, float* __restrict__ vi, float* __restrict__ cnt)
{
    __shared__ float hcnt[Ee];
    const int tid = threadIdx.x;
    if (tid < Ee) hcnt[tid] = 0.0f;
    __syncthreads();

    const int g  = blockIdx.x * 256 + tid;     // 0 .. B*N/4 - 1
    const int b  = g >> 12;                    // 4096 threads per b
    const int n4 = (g & 4095) << 2;            // n offset within b

    const int4   t4 = *reinterpret_cast<const int4*>(tidx + b * Nn + n4);
    const int4   v4 = *reinterpret_cast<const int4*>(vidx + b * Nn + n4);
    const float4 m4 = *reinterpret_cast<const float4*>(mask + b * Nn + n4);

    // LDS histogram of masked nodes per variable hyperedge
    if (m4.x != 0.0f) atomicAdd(&hcnt[v4.x], 1.0f);
    if (m4.y != 0.0f) atomicAdd(&hcnt[v4.y], 1.0f);
    if (m4.z != 0.0f) atomicAdd(&hcnt[v4.z], 1.0f);
    if (m4.w != 0.0f) atomicAdd(&hcnt[v4.w], 1.0f);

    // dense temporal incidence: ti[b,l,n] = (tidx==l) * mask
    float* tib = ti + (((size_t)b * Ll) << 14) + n4;
    #pragma unroll 4
    for (int l = 0; l < Ll; ++l) {
        float4 o;
        o.x = (t4.x == l) ? m4.x : 0.0f;
        o.y = (t4.y == l) ? m4.y : 0.0f;
        o.z = (t4.z == l) ? m4.z : 0.0f;
        o.w = (t4.w == l) ? m4.w : 0.0f;
        *reinterpret_cast<float4*>(tib + ((size_t)l << 14)) = o;
    }

    // dense variable incidence: vi[b,e,n] = (vidx==e) * mask
    float* vib = vi + (((size_t)b * Ee) << 14) + n4;
    #pragma unroll 4
    for (int e = 0; e < Ee; ++e) {
        float4 o;
        o.x = (v4.x == e) ? m4.x : 0.0f;
        o.y = (v4.y == e) ? m4.y : 0.0f;
        o.z = (v4.z == e) ? m4.z : 0.0f;
        o.w = (v4.w == e) ? m4.w : 0.0f;
        *reinterpret_cast<float4*>(vib + ((size_t)e << 14)) = o;
    }

    __syncthreads();
    if (tid < Ee) {
        const float c = hcnt[tid];
        if (c != 0.0f) atomicAdd(&cnt[b * Ee + tid], c);
    }
}

// ---------------------------------------------------------------------------
// Kernel 2: obs = relu(feats @ W_obs + b_obs) * mask.  32 lanes per row,
// float4 per thread -> 1 KB coalesced store per wave.
// ---------------------------------------------------------------------------
__global__ __launch_bounds__(256) void k_obs(
    const float* __restrict__ x, const float* __restrict__ mask,
    const float* __restrict__ ymask, const float* __restrict__ W_obs,
    const float* __restrict__ b_obs, float* __restrict__ obs)
{
    const int g   = blockIdx.x * 256 + threadIdx.x;   // over B*N*32
    const int row = g >> 5;
    const int d   = (g & 31) << 2;

    const float m  = mask[row];
    const float xv = x[row];
    const float f1 = 1.0f - m + ymask[row];

    const float4 w0 = *reinterpret_cast<const float4*>(W_obs + d);
    const float4 w1 = *reinterpret_cast<const float4*>(W_obs + Dd + d);
    const float4 bb = *reinterpret_cast<const float4*>(b_obs + d);

    float4 o;
    o.x = fmaxf(fmaf(xv, w0.x, fmaf(f1, w1.x, bb.x)), 0.0f) * m;
    o.y = fmaxf(fmaf(xv, w0.y, fmaf(f1, w1.y, bb.y)), 0.0f) * m;
    o.z = fmaxf(fmaf(xv, w0.z, fmaf(f1, w1.z, bb.z)), 0.0f) * m;
    o.w = fmaxf(fmaf(xv, w0.w, fmaf(f1, w1.w, bb.w)), 0.0f) * m;
    *reinterpret_cast<float4*>(obs + ((size_t)row << 7) + d) = o;
}

// ---------------------------------------------------------------------------
// Kernel 3: temp_he = sin(mark * W_time + b_time), elementwise over B*L*D
// ---------------------------------------------------------------------------
__global__ __launch_bounds__(256) void k_temp(
    const float* __restrict__ mark, const float* __restrict__ Wt,
    const float* __restrict__ bt, float* __restrict__ temp)
{
    const int idx = blockIdx.x * 256 + threadIdx.x;   // < 393216
    const int d = idx & 127;
    const int r = idx >> 7;
    temp[idx] = sinf(fmaf(mark[r], Wt[d], bt[d]));
}

// ---------------------------------------------------------------------------
// Kernel 4: q,k,v = relu(var_w) @ W_{q,k,v} + b  (batch-independent, fp32 ws)
// ---------------------------------------------------------------------------
__global__ __launch_bounds__(128) void k_qkv(
    const float* __restrict__ var_w,
    const float* __restrict__ Wq, const float* __restrict__ bq,
    const float* __restrict__ Wk, const float* __restrict__ bk,
    const float* __restrict__ Wv, const float* __restrict__ bv,
    float* __restrict__ q, float* __restrict__ k, float* __restrict__ v)
{
    __shared__ float h[Dd];
    const int e = blockIdx.x, d = threadIdx.x;
    h[d] = fmaxf(var_w[e * Dd + d], 0.0f);
    __syncthreads();
    float aq = bq[d], ak = bk[d], av = bv[d];
    #pragma unroll 4
    for (int j = 0; j < Dd; ++j) {
        const float hj = h[j];
        aq = fmaf(hj, Wq[j * Dd + d], aq);
        ak = fmaf(hj, Wk[j * Dd + d], ak);
        av = fmaf(hj, Wv[j * Dd + d], av);
    }
    q[e * Dd + d] = aq;
    k[e * Dd + d] = ak;
    v[e * Dd + d] = av;
}

// ---------------------------------------------------------------------------
// Kernel 5: att0 = q @ k^T / sqrt(D)  (batch-independent, fp32)
// ---------------------------------------------------------------------------
__global__ __launch_bounds__(128) void k_att0(
    const float* __restrict__ q, const float* __restrict__ k,
    float* __restrict__ att0)
{
    __shared__ float qr[Dd];
    const int e = blockIdx.x, f = threadIdx.x;
    qr[f] = q[e * Dd + f];
    __syncthreads();
    const float* kr = k + f * Dd;
    float acc = 0.0f;
    #pragma unroll 4
    for (int d = 0; d < Dd; ++d) acc = fmaf(qr[d], kr[d], acc);
    att0[e * Dd + f] = acc * 0.08838834764831845f;   // 1/sqrt(128)
}

// ---------------------------------------------------------------------------
// Kernel 6: per-(b,e): diagonal merge-adjust, softmax over f, out = attn @ v
// ---------------------------------------------------------------------------
__global__ __launch_bounds__(128) void k_soft(
    const float* __restrict__ att0, const float* __restrict__ v,
    const float* __restrict__ cnt, const float* __restrict__ thr_p,
    const float* __restrict__ mc_p, const int* __restrict__ nobs_p,
    float* __restrict__ outp)
{
    __shared__ float attn[Ee];
    __shared__ float red[4];
    const int b = blockIdx.x >> 7;
    const int e = blockIdx.x & 127;
    const int f = threadIdx.x;

    float a = att0[e * Ee + f];
    if (f == e) {
        const float c = cnt[b * Ee + e];
        const float thr = *thr_p;
        if (c != 0.0f && a > thr) {
            const float mc  = *mc_p;
            const float aux = c / sqrtf((float)(*nobs_p));
            a = (1.0f - mc) * a + mc * aux;
        }
    }
    float mx = a;
    #pragma unroll
    for (int off = 32; off > 0; off >>= 1) mx = fmaxf(mx, __shfl_xor(mx, off));
    if ((threadIdx.x & 63) == 0) red[threadIdx.x >> 6] = mx;
    __syncthreads();
    mx = fmaxf(red[0], red[1]);

    const float ex = expf(a - mx);
    float s = ex;
    #pragma unroll
    for (int off = 32; off > 0; off >>= 1) s += __shfl_xor(s, off);
    if ((threadIdx.x & 63) == 0) red[2 + (threadIdx.x >> 6)] = s;
    __syncthreads();
    s = red[2] + red[3];

    attn[f] = ex / s;
    __syncthreads();

    const int d = f;
    float acc = 0.0f;
    #pragma unroll 4
    for (int j = 0; j < Ee; ++j) acc = fmaf(attn[j], v[j * Dd + d], acc);
    outp[((size_t)(b * Ee + e) << 7) + d] = acc;
}

// ---------------------------------------------------------------------------
extern "C" void kernel_launch(void* const* d_in, const int* in_sizes, int n_in,
                              void* d_out, int out_size, void* d_ws, size_t ws_size,
                              hipStream_t stream) {
    (void)in_sizes; (void)n_in; (void)out_size; (void)ws_size;

    const float* x      = (const float*)d_in[0];
    const float* mask   = (const float*)d_in[1];
    const float* ymask  = (const float*)d_in[2];
    const float* mark   = (const float*)d_in[3];
    const int*   vidx   = (const int*)d_in[4];
    const int*   tidx   = (const int*)d_in[5];
    const int*   nobs   = (const int*)d_in[6];
    const float* W_obs  = (const float*)d_in[7];
    const float* b_obs  = (const float*)d_in[8];
    const float* W_time = (const float*)d_in[9];
    const float* b_time = (const float*)d_in[10];
    const float* var_w  = (const float*)d_in[11];
    const float* W_q    = (const float*)d_in[12];
    const float* b_q    = (const float*)d_in[13];
    const float* W_k    = (const float*)d_in[14];
    const float* b_k    = (const float*)d_in[15];
    const float* W_v    = (const float*)d_in[16];
    const float* b_v    = (const float*)d_in[17];
    const float* thr    = (const float*)d_in[18];
    const float* mc     = (const float*)d_in[19];

    float* out_base = (float*)d_out;
    float* obs  = out_base;
    float* temp = out_base + 33554432;
    float* attO = out_base + 33947648;
    float* ti   = out_base + 34209792;
    float* vi   = out_base + 84541440;

    // ws layout (fp32): cnt[2048] | q[16384] | k[16384] | v[16384] | att0[16384]
    float* ws   = (float*)d_ws;
    float* cnt  = ws;
    float* q    = ws + 2048;
    float* k    = ws + 18432;
    float* v    = ws + 34816;
    float* att0 = ws + 51200;

    hipMemsetAsync(cnt, 0, 2048 * sizeof(float), stream);

    k_inc<<<(Bb * Nn) / (4 * 256), 256, 0, stream>>>(tidx, vidx, mask, ti, vi, cnt);
    k_obs<<<(Bb * Nn * 32) / 256, 256, 0, stream>>>(x, mask, ymask, W_obs, b_obs, obs);
    k_temp<<<(Bb * Ll * Dd) / 256, 256, 0, stream>>>(mark, W_time, b_time, temp);
    k_qkv<<<Ee, Dd, 0, stream>>>(var_w, W_q, b_q, W_k, b_k, W_v, b_v, q, k, v);
    k_att0<<<Ee, Dd, 0, stream>>>(q, k, att0);
    k_soft<<<Bb * Ee, Dd, 0, stream>>>(att0, v, cnt, thr, mc, nobs, attO);
}

// Round 6
// 583.167 us; speedup vs baseline: 1.1034x; 1.0133x over previous
//
#include <hip/hip_runtime.h>

// Problem constants
#define Bb 16
#define Nn 16384
#define Ll 192
#define Ee 128
#define Dd 128

// Output element offsets (fp32 elements) within d_out:
// obs:     0          (16*16384*128 = 33554432)
// temp_he: 33554432   (16*192*128   =   393216)
// out:     33947648   (16*128*128   =   262144)
// ti:      34209792   (16*192*16384 = 50331648)
// vi:      84541440   (16*128*16384 = 33554432)   [ti+vi contiguous]

// ---------------------------------------------------------------------------
// Kernel 1 (k_front): blocks [0,1024): dense ti/vi incidence (4-way split of
// the l/e loops for occupancy) + per-block-quarter histogram partials.
// Blocks [1024,1152): q,kT,v = relu(var_w) @ W_{q,k,v} + b (batch-indep).
// No memset, no global atomics: partials written unconditionally over poison.
// ---------------------------------------------------------------------------
__global__ __launch_bounds__(256) void k_front(
    const int* __restrict__ tidx, const int* __restrict__ vidx,
    const float* __restrict__ mask, const float* __restrict__ var_w,
    const float* __restrict__ Wq, const float* __restrict__ bq,
    const float* __restrict__ Wk, const float* __restrict__ bk,
    const float* __restrict__ Wv, const float* __restrict__ bv,
    float* __restrict__ ti, float* __restrict__ vi,
    float* __restrict__ cnt_part,          // [256][128]
    float* __restrict__ q, float* __restrict__ kT, float* __restrict__ v)
{
    __shared__ float sh[Ee];
    const int tid = threadIdx.x;

    if (blockIdx.x < 1024) {
        const int pb      = blockIdx.x >> 2;   // 0..255: n-range owner
        const int quarter = blockIdx.x & 3;
        const int g  = pb * 256 + tid;         // 0 .. B*N/4 - 1
        const int b  = g >> 12;                // 4096 threads per b
        const int n4 = (g & 4095) << 2;

        const int4   t4 = *reinterpret_cast<const int4*>(tidx + b * Nn + n4);
        const int4   v4 = *reinterpret_cast<const int4*>(vidx + b * Nn + n4);
        const float4 m4 = *reinterpret_cast<const float4*>(mask + b * Nn + n4);

        // quarter 0 also produces the per-(pb,e) histogram partial
        if (quarter == 0) {
            if (tid < Ee) sh[tid] = 0.0f;
            __syncthreads();
            if (m4.x != 0.0f) atomicAdd(&sh[v4.x], 1.0f);
            if (m4.y != 0.0f) atomicAdd(&sh[v4.y], 1.0f);
            if (m4.z != 0.0f) atomicAdd(&sh[v4.z], 1.0f);
            if (m4.w != 0.0f) atomicAdd(&sh[v4.w], 1.0f);
        }

        // temporal incidence: 48 l-planes per quarter
        const int l0 = quarter * 48;
        float* tib = ti + (((size_t)b * Ll) << 14) + n4;
        #pragma unroll 4
        for (int l = l0; l < l0 + 48; ++l) {
            float4 o;
            o.x = (t4.x == l) ? m4.x : 0.0f;
            o.y = (t4.y == l) ? m4.y : 0.0f;
            o.z = (t4.z == l) ? m4.z : 0.0f;
            o.w = (t4.w == l) ? m4.w : 0.0f;
            *reinterpret_cast<float4*>(tib + ((size_t)l << 14)) = o;
        }

        // variable incidence: 32 e-planes per quarter
        const int e0 = quarter * 32;
        float* vib = vi + (((size_t)b * Ee) << 14) + n4;
        #pragma unroll 4
        for (int e = e0; e < e0 + 32; ++e) {
            float4 o;
            o.x = (v4.x == e) ? m4.x : 0.0f;
            o.y = (v4.y == e) ? m4.y : 0.0f;
            o.z = (v4.z == e) ? m4.z : 0.0f;
            o.w = (v4.w == e) ? m4.w : 0.0f;
            *reinterpret_cast<float4*>(vib + ((size_t)e << 14)) = o;
        }

        if (quarter == 0) {
            __syncthreads();
            if (tid < Ee) cnt_part[pb * Ee + tid] = sh[tid];
        }
    } else {
        // qkv path: one hyperedge row e per block, threads 0..127 active
        const int e = blockIdx.x - 1024;
        const int d = tid;
        if (d < Dd) sh[d] = fmaxf(var_w[e * Dd + d], 0.0f);
        __syncthreads();
        if (d < Dd) {
            float aq = bq[d], ak = bk[d], av = bv[d];
            #pragma unroll 4
            for (int j = 0; j < Dd; ++j) {
                const float hj = sh[j];
                aq = fmaf(hj, Wq[j * Dd + d], aq);
                ak = fmaf(hj, Wk[j * Dd + d], ak);
                av = fmaf(hj, Wv[j * Dd + d], av);
            }
            q[e * Dd + d]  = aq;
            kT[d * Dd + e] = ak;   // transposed for coalesced k_soft reads
            v[e * Dd + d]  = av;
        }
    }
}

// ---------------------------------------------------------------------------
// Kernel 2 (k_back): blocks [0,32768): obs = relu(feats@W_obs+b)*mask,
// 32 lanes/row x float4 (B*N*32 = 8388608 threads). Blocks [32768,34304):
// temp_he = sin(mark*W_time + b_time) over B*L*D = 393216 elements.
// ---------------------------------------------------------------------------
__global__ __launch_bounds__(256) void k_back(
    const float* __restrict__ x, const float* __restrict__ mask,
    const float* __restrict__ ymask, const float* __restrict__ W_obs,
    const float* __restrict__ b_obs, const float* __restrict__ mark,
    const float* __restrict__ Wt, const float* __restrict__ bt,
    float* __restrict__ obs, float* __restrict__ temp)
{
    if (blockIdx.x < 32768) {
        const int g   = blockIdx.x * 256 + threadIdx.x;   // over B*N*32
        const int row = g >> 5;
        const int d   = (g & 31) << 2;

        const float m  = mask[row];
        const float xv = x[row];
        const float f1 = 1.0f - m + ymask[row];

        const float4 w0 = *reinterpret_cast<const float4*>(W_obs + d);
        const float4 w1 = *reinterpret_cast<const float4*>(W_obs + Dd + d);
        const float4 bb = *reinterpret_cast<const float4*>(b_obs + d);

        float4 o;
        o.x = fmaxf(fmaf(xv, w0.x, fmaf(f1, w1.x, bb.x)), 0.0f) * m;
        o.y = fmaxf(fmaf(xv, w0.y, fmaf(f1, w1.y, bb.y)), 0.0f) * m;
        o.z = fmaxf(fmaf(xv, w0.z, fmaf(f1, w1.z, bb.z)), 0.0f) * m;
        o.w = fmaxf(fmaf(xv, w0.w, fmaf(f1, w1.w, bb.w)), 0.0f) * m;
        *reinterpret_cast<float4*>(obs + ((size_t)row << 7) + d) = o;
    } else {
        const int idx = (blockIdx.x - 32768) * 256 + threadIdx.x; // < 393216
        const int d = idx & 127;
        const int r = idx >> 7;
        temp[idx] = sinf(fmaf(mark[r], Wt[d], bt[d]));
    }
}

// ---------------------------------------------------------------------------
// Kernel 3 (k_soft): per-(b,e) block: fused att-row (q[e]·kT), count-partial
// reduction, diagonal merge-adjust, softmax over f, out = attn @ v.
// ---------------------------------------------------------------------------
__global__ __launch_bounds__(128) void k_soft(
    const float* __restrict__ q, const float* __restrict__ kT,
    const float* __restrict__ v, const float* __restrict__ cnt_part,
    const float* __restrict__ thr_p, const float* __restrict__ mc_p,
    const int* __restrict__ nobs_p, float* __restrict__ outp)
{
    __shared__ float qr[Dd];
    __shared__ float attn[Ee];
    __shared__ float red[5];
    const int b = blockIdx.x >> 7;
    const int e = blockIdx.x & 127;
    const int f = threadIdx.x;

    qr[f] = q[e * Dd + f];

    // sum the 16 histogram partials for (b,e): lanes 0..15 of wave 0
    float cp = (f < 16) ? cnt_part[(b * 16 + f) * Ee + e] : 0.0f;
    #pragma unroll
    for (int off = 8; off > 0; off >>= 1) cp += __shfl_xor(cp, off);
    if (f == 0) red[4] = cp;
    __syncthreads();

    // att0[e,f] = dot(q[e], k[f]) / sqrt(D); kT read is lane-coalesced
    float acc0 = 0.0f;
    #pragma unroll 4
    for (int d = 0; d < Dd; ++d) acc0 = fmaf(qr[d], kT[d * Dd + f], acc0);
    float a = acc0 * 0.08838834764831845f;   // 1/sqrt(128)

    if (f == e) {
        const float c = red[4];
        const float thr = *thr_p;
        if (c != 0.0f && a > thr) {
            const float mc  = *mc_p;
            const float aux = c / sqrtf((float)(*nobs_p));
            a = (1.0f - mc) * a + mc * aux;
        }
    }

    // block max (2 waves)
    float mx = a;
    #pragma unroll
    for (int off = 32; off > 0; off >>= 1) mx = fmaxf(mx, __shfl_xor(mx, off));
    if ((f & 63) == 0) red[f >> 6] = mx;
    __syncthreads();
    mx = fmaxf(red[0], red[1]);

    const float ex = expf(a - mx);
    float s = ex;
    #pragma unroll
    for (int off = 32; off > 0; off >>= 1) s += __shfl_xor(s, off);
    if ((f & 63) == 0) red[2 + (f >> 6)] = s;
    __syncthreads();
    s = red[2] + red[3];

    attn[f] = ex / s;
    __syncthreads();

    const int d = f;
    float acc = 0.0f;
    #pragma unroll 4
    for (int j = 0; j < Ee; ++j) acc = fmaf(attn[j], v[j * Dd + d], acc);
    outp[((size_t)(b * Ee + e) << 7) + d] = acc;
}

// ---------------------------------------------------------------------------
extern "C" void kernel_launch(void* const* d_in, const int* in_sizes, int n_in,
                              void* d_out, int out_size, void* d_ws, size_t ws_size,
                              hipStream_t stream) {
    (void)in_sizes; (void)n_in; (void)out_size; (void)ws_size;

    const float* x      = (const float*)d_in[0];
    const float* mask   = (const float*)d_in[1];
    const float* ymask  = (const float*)d_in[2];
    const float* mark   = (const float*)d_in[3];
    const int*   vidx   = (const int*)d_in[4];
    const int*   tidx   = (const int*)d_in[5];
    const int*   nobs   = (const int*)d_in[6];
    const float* W_obs  = (const float*)d_in[7];
    const float* b_obs  = (const float*)d_in[8];
    const float* W_time = (const float*)d_in[9];
    const float* b_time = (const float*)d_in[10];
    const float* var_w  = (const float*)d_in[11];
    const float* W_q    = (const float*)d_in[12];
    const float* b_q    = (const float*)d_in[13];
    const float* W_k    = (const float*)d_in[14];
    const float* b_k    = (const float*)d_in[15];
    const float* W_v    = (const float*)d_in[16];
    const float* b_v    = (const float*)d_in[17];
    const float* thr    = (const float*)d_in[18];
    const float* mc     = (const float*)d_in[19];

    float* out_base = (float*)d_out;
    float* obs  = out_base;
    float* temp = out_base + 33554432;
    float* attO = out_base + 33947648;
    float* ti   = out_base + 34209792;
    float* vi   = out_base + 84541440;

    // ws layout (fp32): cnt_part[256*128] | q[16384] | kT[16384] | v[16384]
    float* ws       = (float*)d_ws;
    float* cnt_part = ws;
    float* q        = ws + 32768;
    float* kT       = ws + 49152;
    float* v        = ws + 65536;

    k_front<<<1024 + 128, 256, 0, stream>>>(tidx, vidx, mask, var_w,
                                            W_q, b_q, W_k, b_k, W_v, b_v,
                                            ti, vi, cnt_part, q, kT, v);
    k_back<<<32768 + 1536, 256, 0, stream>>>(x, mask, ymask, W_obs, b_obs,
                                             mark, W_time, b_time, obs, temp);
    k_soft<<<Bb * Ee, Dd, 0, stream>>>(q, kT, v, cnt_part, thr, mc, nobs, attO);
}

// Round 7
// 572.072 us; speedup vs baseline: 1.1248x; 1.0194x over previous
//
#include <hip/hip_runtime.h>

// Problem constants
#define Bb 16
#define Nn 16384
#define Ll 192
#define Ee 128
#define Dd 128

// Output element offsets (fp32 elements) within d_out:
// obs:     0          (16*16384*128 = 33554432)
// temp_he: 33554432   (16*192*128   =   393216)
// out:     33947648   (16*128*128   =   262144)
// ti:      34209792   (16*192*16384 = 50331648)
// vi:      84541440   (16*128*16384 = 33554432)   [ti+vi contiguous]

// ---------------------------------------------------------------------------
// Kernel 1 (k_main) — all independent write-bound work in one dispatch:
//   blocks [    0, 1024): dense ti/vi incidence (4-way plane split) +
//                         per-(pb,e) histogram partials (quarter 0)
//   blocks [ 1024, 1152): q,kT,v = relu(var_w) @ W_{q,k,v} + b
//   blocks [ 1152,33920): obs = relu(feats @ W_obs + b_obs) * mask
//   blocks [33920,35456): temp_he = sin(mark * W_time + b_time)
// ---------------------------------------------------------------------------
__global__ __launch_bounds__(256) void k_main(
    const int* __restrict__ tidx, const int* __restrict__ vidx,
    const float* __restrict__ mask, const float* __restrict__ var_w,
    const float* __restrict__ Wq, const float* __restrict__ bq,
    const float* __restrict__ Wk, const float* __restrict__ bk,
    const float* __restrict__ Wv, const float* __restrict__ bv,
    const float* __restrict__ x, const float* __restrict__ ymask,
    const float* __restrict__ W_obs, const float* __restrict__ b_obs,
    const float* __restrict__ mark, const float* __restrict__ Wt,
    const float* __restrict__ bt,
    float* __restrict__ ti, float* __restrict__ vi,
    float* __restrict__ cnt_part,          // [256][128]
    float* __restrict__ q, float* __restrict__ kT, float* __restrict__ v,
    float* __restrict__ obs, float* __restrict__ temp)
{
    __shared__ float sh[Ee];
    const int tid = threadIdx.x;

    if (blockIdx.x < 1024) {
        const int pb      = blockIdx.x >> 2;   // 0..255: n-range owner
        const int quarter = blockIdx.x & 3;
        const int g  = pb * 256 + tid;         // 0 .. B*N/4 - 1
        const int b  = g >> 12;                // 4096 threads per b
        const int n4 = (g & 4095) << 2;

        const int4   t4 = *reinterpret_cast<const int4*>(tidx + b * Nn + n4);
        const int4   v4 = *reinterpret_cast<const int4*>(vidx + b * Nn + n4);
        const float4 m4 = *reinterpret_cast<const float4*>(mask + b * Nn + n4);

        // quarter 0 also produces the per-(pb,e) histogram partial
        if (quarter == 0) {
            if (tid < Ee) sh[tid] = 0.0f;
            __syncthreads();
            if (m4.x != 0.0f) atomicAdd(&sh[v4.x], 1.0f);
            if (m4.y != 0.0f) atomicAdd(&sh[v4.y], 1.0f);
            if (m4.z != 0.0f) atomicAdd(&sh[v4.z], 1.0f);
            if (m4.w != 0.0f) atomicAdd(&sh[v4.w], 1.0f);
        }

        // temporal incidence: 48 l-planes per quarter
        const int l0 = quarter * 48;
        float* tib = ti + (((size_t)b * Ll) << 14) + n4;
        #pragma unroll 4
        for (int l = l0; l < l0 + 48; ++l) {
            float4 o;
            o.x = (t4.x == l) ? m4.x : 0.0f;
            o.y = (t4.y == l) ? m4.y : 0.0f;
            o.z = (t4.z == l) ? m4.z : 0.0f;
            o.w = (t4.w == l) ? m4.w : 0.0f;
            *reinterpret_cast<float4*>(tib + ((size_t)l << 14)) = o;
        }

        // variable incidence: 32 e-planes per quarter
        const int e0 = quarter * 32;
        float* vib = vi + (((size_t)b * Ee) << 14) + n4;
        #pragma unroll 4
        for (int e = e0; e < e0 + 32; ++e) {
            float4 o;
            o.x = (v4.x == e) ? m4.x : 0.0f;
            o.y = (v4.y == e) ? m4.y : 0.0f;
            o.z = (v4.z == e) ? m4.z : 0.0f;
            o.w = (v4.w == e) ? m4.w : 0.0f;
            *reinterpret_cast<float4*>(vib + ((size_t)e << 14)) = o;
        }

        if (quarter == 0) {
            __syncthreads();
            if (tid < Ee) cnt_part[pb * Ee + tid] = sh[tid];
        }
    } else if (blockIdx.x < 1152) {
        // qkv path: one hyperedge row e per block, threads 0..127 active
        const int e = blockIdx.x - 1024;
        const int d = tid;
        if (d < Dd) sh[d] = fmaxf(var_w[e * Dd + d], 0.0f);
        __syncthreads();
        if (d < Dd) {
            float aq = bq[d], ak = bk[d], av = bv[d];
            #pragma unroll 4
            for (int j = 0; j < Dd; ++j) {
                const float hj = sh[j];
                aq = fmaf(hj, Wq[j * Dd + d], aq);
                ak = fmaf(hj, Wk[j * Dd + d], ak);
                av = fmaf(hj, Wv[j * Dd + d], av);
            }
            q[e * Dd + d]  = aq;
            kT[d * Dd + e] = ak;   // transposed for coalesced k_soft reads
            v[e * Dd + d]  = av;
        }
    } else if (blockIdx.x < 33920) {
        const int g   = (blockIdx.x - 1152) * 256 + tid;   // over B*N*32
        const int row = g >> 5;
        const int d   = (g & 31) << 2;

        const float m  = mask[row];
        const float xv = x[row];
        const float f1 = 1.0f - m + ymask[row];

        const float4 w0 = *reinterpret_cast<const float4*>(W_obs + d);
        const float4 w1 = *reinterpret_cast<const float4*>(W_obs + Dd + d);
        const float4 bb = *reinterpret_cast<const float4*>(b_obs + d);

        float4 o;
        o.x = fmaxf(fmaf(xv, w0.x, fmaf(f1, w1.x, bb.x)), 0.0f) * m;
        o.y = fmaxf(fmaf(xv, w0.y, fmaf(f1, w1.y, bb.y)), 0.0f) * m;
        o.z = fmaxf(fmaf(xv, w0.z, fmaf(f1, w1.z, bb.z)), 0.0f) * m;
        o.w = fmaxf(fmaf(xv, w0.w, fmaf(f1, w1.w, bb.w)), 0.0f) * m;
        *reinterpret_cast<float4*>(obs + ((size_t)row << 7) + d) = o;
    } else {
        const int idx = (blockIdx.x - 33920) * 256 + tid;  // < 393216
        const int d = idx & 127;
        const int r = idx >> 7;
        temp[idx] = sinf(fmaf(mark[r], Wt[d], bt[d]));
    }
}

// ---------------------------------------------------------------------------
// Kernel 2 (k_soft): per-(b,e) block: fused att-row (q[e]·kT), count-partial
// reduction, diagonal merge-adjust, softmax over f, out = attn @ v.
// ---------------------------------------------------------------------------
__global__ __launch_bounds__(128) void k_soft(
    const float* __restrict__ q, const float* __restrict__ kT,
    const float* __restrict__ v, const float* __restrict__ cnt_part,
    const float* __restrict__ thr_p, const float* __restrict__ mc_p,
    const int* __restrict__ nobs_p, float* __restrict__ outp)
{
    __shared__ float qr[Dd];
    __shared__ float attn[Ee];
    __shared__ float red[5];
    const int b = blockIdx.x >> 7;
    const int e = blockIdx.x & 127;
    const int f = threadIdx.x;

    qr[f] = q[e * Dd + f];

    // sum the 16 histogram partials for (b,e): lanes 0..15 of wave 0
    float cp = (f < 16) ? cnt_part[(b * 16 + f) * Ee + e] : 0.0f;
    #pragma unroll
    for (int off = 8; off > 0; off >>= 1) cp += __shfl_xor(cp, off);
    if (f == 0) red[4] = cp;
    __syncthreads();

    // att0[e,f] = dot(q[e], k[f]) / sqrt(D); kT read is lane-coalesced
    float acc0 = 0.0f;
    #pragma unroll 4
    for (int d = 0; d < Dd; ++d) acc0 = fmaf(qr[d], kT[d * Dd + f], acc0);
    float a = acc0 * 0.08838834764831845f;   // 1/sqrt(128)

    if (f == e) {
        const float c = red[4];
        const float thr = *thr_p;
        if (c != 0.0f && a > thr) {
            const float mc  = *mc_p;
            const float aux = c / sqrtf((float)(*nobs_p));
            a = (1.0f - mc) * a + mc * aux;
        }
    }

    // block max (2 waves)
    float mx = a;
    #pragma unroll
    for (int off = 32; off > 0; off >>= 1) mx = fmaxf(mx, __shfl_xor(mx, off));
    if ((f & 63) == 0) red[f >> 6] = mx;
    __syncthreads();
    mx = fmaxf(red[0], red[1]);

    const float ex = expf(a - mx);
    float s = ex;
    #pragma unroll
    for (int off = 32; off > 0; off >>= 1) s += __shfl_xor(s, off);
    if ((f & 63) == 0) red[2 + (f >> 6)] = s;
    __syncthreads();
    s = red[2] + red[3];

    attn[f] = ex / s;
    __syncthreads();

    const int d = f;
    float acc = 0.0f;
    #pragma unroll 4
    for (int j = 0; j < Ee; ++j) acc = fmaf(attn[j], v[j * Dd + d], acc);
    outp[((size_t)(b * Ee + e) << 7) + d] = acc;
}

// ---------------------------------------------------------------------------
extern "C" void kernel_launch(void* const* d_in, const int* in_sizes, int n_in,
                              void* d_out, int out_size, void* d_ws, size_t ws_size,
                              hipStream_t stream) {
    (void)in_sizes; (void)n_in; (void)out_size; (void)ws_size;

    const float* x      = (const float*)d_in[0];
    const float* mask   = (const float*)d_in[1];
    const float* ymask  = (const float*)d_in[2];
    const float* mark   = (const float*)d_in[3];
    const int*   vidx   = (const int*)d_in[4];
    const int*   tidx   = (const int*)d_in[5];
    const int*   nobs   = (const int*)d_in[6];
    const float* W_obs  = (const float*)d_in[7];
    const float* b_obs  = (const float*)d_in[8];
    const float* W_time = (const float*)d_in[9];
    const float* b_time = (const float*)d_in[10];
    const float* var_w  = (const float*)d_in[11];
    const float* W_q    = (const float*)d_in[12];
    const float* b_q    = (const float*)d_in[13];
    const float* W_k    = (const float*)d_in[14];
    const float* b_k    = (const float*)d_in[15];
    const float* W_v    = (const float*)d_in[16];
    const float* b_v    = (const float*)d_in[17];
    const float* thr    = (const float*)d_in[18];
    const float* mc     = (const float*)d_in[19];

    float* out_base = (float*)d_out;
    float* obs  = out_base;
    float* temp = out_base + 33554432;
    float* attO = out_base + 33947648;
    float* ti   = out_base + 34209792;
    float* vi   = out_base + 84541440;

    // ws layout (fp32): cnt_part[256*128] | q[16384] | kT[16384] | v[16384]
    float* ws       = (float*)d_ws;
    float* cnt_part = ws;
    float* q        = ws + 32768;
    float* kT       = ws + 49152;
    float* v        = ws + 65536;

    k_main<<<35456, 256, 0, stream>>>(tidx, vidx, mask, var_w,
                                      W_q, b_q, W_k, b_k, W_v, b_v,
                                      x, ymask, W_obs, b_obs,
                                      mark, W_time, b_time,
                                      ti, vi, cnt_part, q, kT, v, obs, temp);
    k_soft<<<Bb * Ee, Dd, 0, stream>>>(q, kT, v, cnt_part, thr, mc, nobs, attO);
}